// Round 1
// baseline (916.350 us; speedup 1.0000x reference)
//
#include <hip/hip_runtime.h>
#include <stdint.h>
#include <stddef.h>

// SparseNet on MI355X: per-batch block, sparse conv1 via compacted pair lists
// + v_dot2_f32_f16, f16 LDS staging, fused pools/conv2/head in one kernel.

typedef _Float16 h2v __attribute__((ext_vector_type(2)));
union HU { uint32_t u; h2v h; };

__device__ __forceinline__ float dot2f(uint32_t a, uint32_t b, float c) {
  HU ua, ub; ua.u = a; ub.u = b;
#if __has_builtin(__builtin_amdgcn_fdot2)
  return __builtin_amdgcn_fdot2(ua.h, ub.h, c, false);
#else
  return c + (float)ua.h.x * (float)ub.h.x + (float)ua.h.y * (float)ub.h.y;
#endif
}

struct __align__(16) SMem {
  union {
    struct {
      uint32_t feat2[112 * 100];   // [slot][cin2] half2-packed, row = 400 B (16B aligned)
      uint32_t w1s[16 * 100];      // [c][cin2] half2-packed, one tap at a time
    } a;
    struct {
      uint32_t w2t[32 * 204];      // [c][tap*8+cin2] half2-packed, row padded to 204 (816 B, 16B aligned)
    } b;
  } u;                             // 51200 B
  _Float16 h1[225 * 16];           // dense conv1 out (masked: b1+acc, else -3e4)  7200 B
  _Float16 h1p[49 * 16];           // pool1 out (7,7,16), zeros where !m1          1568 B
  float    h2[9 * 32];             // conv2 out (3,3,32)                           1152 B
  float    vp[32];                 // pool2 out                                     128 B
  short    pts[112];               // slot -> pos (y*15+x)
  short    slotmap[225];           // pos -> slot or -1
  unsigned short lst[112];         // per-tap pair list: (out_slot<<7)|src_slot
  int      cnt[9];                 // per-tap pair counts (zeroed once)
  unsigned char m1[49];
  unsigned char m2[9];
};

extern "C" __global__ void __launch_bounds__(256)
spnet_kernel(const int* __restrict__ coords, const float* __restrict__ feats,
             const float* __restrict__ W1, const float* __restrict__ b1,
             const float* __restrict__ W2, const float* __restrict__ linW,
             const float* __restrict__ linb, float* __restrict__ out)
{
  __shared__ SMem s;
  const int t = threadIdx.x;
  const int b = blockIdx.x;

  // ---- phase 0: init slotmap / counters ----
  for (int i = t; i < 225; i += 256) s.slotmap[i] = -1;
  if (t < 9) s.cnt[t] = 0;
  __syncthreads();

  // ---- phase 1: coords -> pts/slotmap ----
  if (t < 112) {
    const int r = (b * 112 + t) * 3;
    const int y = coords[r], x = coords[r + 1];
    const short pos = (short)(y * 15 + x);
    s.pts[t] = pos;
    s.slotmap[pos] = (short)t;
  }
  __syncthreads();

  // ---- phase 2a: h1 init (bias at masked, NEG sentinel elsewhere) ----
  {
    const float bc = b1[t & 15];          // i%16 == t%16 for all strided i (256 % 16 == 0)
    const _Float16 bh = (_Float16)bc;
    const _Float16 ng = (_Float16)(-30000.0f);
    for (int i = t; i < 3600; i += 256)
      s.h1[i] = (s.slotmap[i >> 4] >= 0) ? bh : ng;
  }

  // ---- phase 2b: stage features -> packed f16 pairs (the 367 MB HBM stream) ----
  {
    const float4* fsrc = (const float4*)(feats + (size_t)b * (112 * 200));
    uint2* fdst = (uint2*)s.u.a.feat2;
    for (int i = t; i < 5600; i += 256) {
      const float4 v = fsrc[i];
      HU p0, p1;
      p0.h.x = (_Float16)v.x; p0.h.y = (_Float16)v.y;
      p1.h.x = (_Float16)v.z; p1.h.y = (_Float16)v.w;
      fdst[i] = make_uint2(p0.u, p1.u);
    }
  }

  const int c16 = t & 15;       // output channel (conv1)
  const int g16 = t >> 4;       // pair-entry group (0..15)

  // ---- conv1: loop over 9 taps ----
  for (int tap = 0; tap < 9; ++tap) {
    // stage W1[tap] -> w1s[c][cin2], coalesced global reads (c fastest)
    const float* w1g = W1 + tap * (200 * 16);
    for (int j = t; j < 1600; j += 256) {
      const int c = j & 15, q = j >> 4;   // q = cin2 in 0..99
      HU p;
      p.h.x = (_Float16)w1g[(2 * q) * 16 + c];
      p.h.y = (_Float16)w1g[(2 * q + 1) * 16 + c];
      s.u.a.w1s[c * 100 + q] = p.u;
    }
    // build compacted (out,src) pair list for this tap
    if (t < 112) {
      const int pos = s.pts[t];
      const int y = pos / 15, x = pos - y * 15;
      const int ky = tap / 3, kx = tap - ky * 3;
      const int iy = y + ky - 1, ix = x + kx - 1;   // SAME conv, pad=1
      if (iy >= 0 && iy < 15 && ix >= 0 && ix < 15) {
        const int sl = s.slotmap[iy * 15 + ix];
        if (sl >= 0) {
          const int idx = atomicAdd(&s.cnt[tap], 1);
          s.lst[idx] = (unsigned short)((t << 7) | sl);
        }
      }
    }
    __syncthreads();

    const int n = s.cnt[tap];
    for (int e = g16; e < n; e += 16) {
      const int pr = s.lst[e];
      const int o = pr >> 7, sl = pr & 127;
      const uint4* fa = (const uint4*)(s.u.a.feat2 + sl * 100); // 16-way lane broadcast
      const uint4* wa = (const uint4*)(s.u.a.w1s + c16 * 100);  // 4-way broadcast, 2-way banks
      float a0 = 0.f, a1 = 0.f, a2 = 0.f, a3 = 0.f;
      #pragma unroll
      for (int q = 0; q < 25; ++q) {
        const uint4 fv = fa[q];
        const uint4 wv = wa[q];
        a0 = dot2f(fv.x, wv.x, a0);
        a1 = dot2f(fv.y, wv.y, a1);
        a2 = dot2f(fv.z, wv.z, a2);
        a3 = dot2f(fv.w, wv.w, a3);
      }
      const float acc = (a0 + a1) + (a2 + a3);
      const int hp = (int)s.pts[o] * 16 + c16;   // unique (o,c) per tap -> race-free RMW
      s.h1[hp] = (_Float16)((float)s.h1[hp] + acc);
    }
    __syncthreads();
  }

  // ---- pool1: 3x3 stride-2 max-or -> h1p (7,7,16), m1 ----
  for (int i = t; i < 784; i += 256) {
    const int pp = i >> 4, c = i & 15;
    const int py = pp / 7, px = pp - py * 7;
    const int y0 = 2 * py, x0 = 2 * px;
    float mv = -1e30f;
    int m = 0;
    #pragma unroll
    for (int ky = 0; ky < 3; ++ky)
      #pragma unroll
      for (int kx = 0; kx < 3; ++kx) {
        const int pos = (y0 + ky) * 15 + (x0 + kx);
        m |= (s.slotmap[pos] >= 0) ? 1 : 0;
        mv = fmaxf(mv, (float)s.h1[pos * 16 + c]);
      }
    s.h1p[i] = (_Float16)(m ? mv : 0.f);
    if (c == 0) s.m1[pp] = (unsigned char)m;
  }

  // ---- stage W2 -> w2t (overwrites feat2 region; last union read was before
  //      the tap-loop's trailing barrier, so this is race-free) ----
  for (int j = t; j < 6400; j += 256) {
    const int c = j & 31, q = j >> 5;       // q = tap*8 + cin2
    const int tp = q >> 3, cin2 = q & 7;
    HU p;
    p.h.x = (_Float16)W2[(tp * 16 + 2 * cin2) * 32 + c];
    p.h.y = (_Float16)W2[(tp * 16 + 2 * cin2 + 1) * 32 + c];
    s.u.b.w2t[c * 204 + q] = p.u;
  }
  __syncthreads();

  // ---- conv2: 5x5 VALID (7,7,16) -> (3,3,32) ----
  for (int p = t; p < 288; p += 256) {
    const int pos = p >> 5, c = p & 31;
    const int oy = pos / 3, ox = pos - oy * 3;
    const uint32_t* wrow = s.u.b.w2t + c * 204;
    const uint32_t* hbase = (const uint32_t*)s.h1p;
    float a0 = 0.f, a1 = 0.f, a2 = 0.f, a3 = 0.f;
    for (int ky = 0; ky < 5; ++ky) {
      #pragma unroll
      for (int kx = 0; kx < 5; ++kx) {
        const int tp = ky * 5 + kx;
        const int ip = (oy + ky) * 7 + (ox + kx);
        const uint4* ha = (const uint4*)(hbase + ip * 8);
        const uint4* wa = (const uint4*)(wrow + tp * 8);
        const uint4 h0 = ha[0], h1v = ha[1];
        const uint4 w0 = wa[0], w1v = wa[1];
        a0 = dot2f(h0.x, w0.x, a0);
        a1 = dot2f(h0.y, w0.y, a1);
        a2 = dot2f(h0.z, w0.z, a2);
        a3 = dot2f(h0.w, w0.w, a3);
        a0 = dot2f(h1v.x, w1v.x, a0);
        a1 = dot2f(h1v.y, w1v.y, a1);
        a2 = dot2f(h1v.z, w1v.z, a2);
        a3 = dot2f(h1v.w, w1v.w, a3);
      }
    }
    s.h2[pos * 32 + c] = (a0 + a1) + (a2 + a3);
  }
  // m2: 5x5 any-pool of m1
  if (t < 9) {
    const int oy = t / 3, ox = t - oy * 3;
    int any = 0;
    for (int ky = 0; ky < 5; ++ky)
      for (int kx = 0; kx < 5; ++kx)
        any |= s.m1[(oy + ky) * 7 + (ox + kx)];
    s.m2[t] = (unsigned char)any;
  }
  __syncthreads();

  // ---- pool2: 3x3 stride-2 on (3,3) == masked max over all 9 ----
  if (t < 32) {
    float best = -1e30f;
    int any = 0;
    #pragma unroll
    for (int pos = 0; pos < 9; ++pos) {
      if (s.m2[pos]) {
        any = 1;
        best = fmaxf(best, s.h2[pos * 32 + t]);
      }
    }
    s.vp[t] = any ? best : 0.f;
  }
  __syncthreads();

  // ---- head: 32 -> 2 linear + softmax ----
  if (t == 0) {
    float l0 = linb[0], l1 = linb[1];
    #pragma unroll
    for (int c = 0; c < 32; ++c) {
      const float v = s.vp[c];
      l0 = fmaf(v, linW[2 * c], l0);
      l1 = fmaf(v, linW[2 * c + 1], l1);
    }
    const float mx = fmaxf(l0, l1);
    const float e0 = expf(l0 - mx), e1 = expf(l1 - mx);
    const float inv = 1.0f / (e0 + e1);
    out[2 * b]     = e0 * inv;
    out[2 * b + 1] = e1 * inv;
  }
}

extern "C" void kernel_launch(void* const* d_in, const int* in_sizes, int n_in,
                              void* d_out, int out_size, void* d_ws, size_t ws_size,
                              hipStream_t stream) {
  const int*   coords = (const int*)d_in[0];
  const float* feats  = (const float*)d_in[1];
  const float* W1     = (const float*)d_in[2];
  const float* b1     = (const float*)d_in[3];
  const float* W2     = (const float*)d_in[4];
  const float* linW   = (const float*)d_in[5];
  const float* linb   = (const float*)d_in[6];
  (void)n_in; (void)d_ws; (void)ws_size; (void)out_size;

  const int B = in_sizes[0] / (112 * 3);   // coords is (B*K, 3), K = 112
  float* o = (float*)d_out;
  spnet_kernel<<<dim3(B), dim3(256), 0, stream>>>(coords, feats, W1, b1, W2, linW, linb, o);
}

// Round 2
// 683.924 us; speedup vs baseline: 1.3398x; 1.3398x over previous
//
#include <hip/hip_runtime.h>
#include <stdint.h>
#include <stddef.h>

// SparseNet on MI355X — R2: conv1/conv2 as MFMA gather-GEMMs.
// conv1: M=112 (7x16 output points), N=16 ch, K=9 taps x 224 (f16-pad of 200),
//        absent neighbors -> zeroed dummy feature row 112. No scatter/atomics.
// Weights pre-transposed to f16 c-major in d_ws by prep kernel (L2-resident).

typedef _Float16 f16x8 __attribute__((ext_vector_type(8)));
typedef float f32x4 __attribute__((ext_vector_type(4)));
union U4H8 { uint4 u; f16x8 h; };

#define W1T_WORDS (9 * 16 * 112)   // [tap][c][112 u32] (224 f16, k>=200 zero)
#define W2T_OFF   16384            // u32 offset of w2t in ws (64 KiB in)
#define W2T_WORDS (32 * 208)       // [c][208 u32] (= 26 taps x 8; tap 25 zero)

extern "C" __global__ void prep_weights(const float* __restrict__ W1,
                                        const float* __restrict__ W2,
                                        uint32_t* __restrict__ ws) {
  const int j = blockIdx.x * 256 + threadIdx.x;
  if (j < W1T_WORDS) {
    const int tap = j / 1792, r = j - tap * 1792;
    const int c = r / 112, q = r - c * 112;       // q = k/2
    const int k0 = 2 * q;
    const float f0 = (k0 < 200) ? W1[(tap * 200 + k0) * 16 + c] : 0.f;
    const float f1 = (k0 + 1 < 200) ? W1[(tap * 200 + k0 + 1) * 16 + c] : 0.f;
    union { uint32_t u; _Float16 h[2]; } p;
    p.h[0] = (_Float16)f0; p.h[1] = (_Float16)f1;
    ws[j] = p.u;
  } else if (j < W1T_WORDS + W2T_WORDS) {
    const int jj = j - W1T_WORDS;
    const int c = jj / 208, q = jj - c * 208;     // q = k/2, k = tap*16+cin
    const int tap = q >> 3;
    const int cin0 = (2 * q) & 15;
    float f0 = 0.f, f1 = 0.f;
    if (tap < 25) {
      f0 = W2[(tap * 16 + cin0) * 32 + c];
      f1 = W2[(tap * 16 + cin0 + 1) * 32 + c];
    }
    union { uint32_t u; _Float16 h[2]; } p;
    p.h[0] = (_Float16)f0; p.h[1] = (_Float16)f1;
    ws[W2T_OFF + jj] = p.u;
  }
}

struct __align__(16) SM {
  uint32_t feat2[113 * 116];  // f16-pair rows, stride 116 u32 (bank ~2-way); row 112 = zeros. 52432 B
  _Float16 h1[225 * 16];      // conv1 out dense: bias+acc at occupied, -3e4 elsewhere. 7200 B
  _Float16 h1p[52 * 16];      // pool1 out (49 rows) + 3 zero pad rows for tap-25 A reads. 1664 B
  float    h2[9 * 32];        // conv2 out. 1152 B
  float    vp[32];
  short    pts[112];          // slot -> pos
  short    slotmap[225];      // pos -> slot | -1
  unsigned char m1[49];
  unsigned char m2[9];
};                            // ~63.3 KB -> 2 blocks/CU

extern "C" __global__ void __launch_bounds__(256, 2)
spnet_main(const int* __restrict__ coords, const float* __restrict__ feats,
           const float* __restrict__ b1, const float* __restrict__ linW,
           const float* __restrict__ linb, const uint32_t* __restrict__ wst,
           float* __restrict__ out)
{
  __shared__ SM s;
  const int t = threadIdx.x, b = blockIdx.x;
  const int lane = t & 63, wv = t >> 6;

  // ---- phase 1: init + feature staging (the 367 MB HBM stream) ----
  for (int i = t; i < 225; i += 256) s.slotmap[i] = -1;
  {
    const _Float16 ng = (_Float16)(-30000.0f);
    for (int i = t; i < 3600; i += 256) s.h1[i] = ng;
  }
  if (t < 116) s.feat2[112 * 116 + t] = 0;                       // dummy row
  for (int i = t; i < 1792; i += 256) {                          // k-pad [100,116)
    const int r = i >> 4;
    s.feat2[r * 116 + 100 + (i & 15)] = 0;
  }
  if (t < 48) s.h1p[49 * 16 + t] = (_Float16)0.f;                // tap-25 pad rows

  int my_y = 0, my_x = 0;
  if (t < 112) {
    const int rr = (b * 112 + t) * 3;
    my_y = coords[rr]; my_x = coords[rr + 1];
    s.pts[t] = (short)(my_y * 15 + my_x);
  }

  {
    const float4* fsrc = (const float4*)(feats + (size_t)b * 22400);
    for (int i = t; i < 5600; i += 256) {
      const int r = i / 50, cc = i - r * 50;                     // 50 float4 per row
      const float4 v = fsrc[i];
      union { uint2 u2; _Float16 h[4]; } p;
      p.h[0] = (_Float16)v.x; p.h[1] = (_Float16)v.y;
      p.h[2] = (_Float16)v.z; p.h[3] = (_Float16)v.w;
      *(uint2*)&s.feat2[r * 116 + cc * 2] = p.u2;                // 8B-aligned
    }
  }
  __syncthreads();

  // ---- phase 2: slotmap population (after -1 init barrier) ----
  if (t < 112) s.slotmap[my_y * 15 + my_x] = (short)t;
  __syncthreads();

  // ---- phase 3: conv1 MFMA. 7 m-groups of 16 output points, K = 9*224 ----
  {
    const int m = lane & 15;     // A row within group; also B column (channel)
    const int q = lane >> 4;     // quad
    const float bias = b1[m];    // C col n == lane&15
    for (int g = wv; g < 7; g += 4) {
      const int o = g * 16 + m;
      const int pos = s.pts[o];
      const int oy = pos / 15, ox = pos - oy * 15;
      f32x4 acc = {0.f, 0.f, 0.f, 0.f};
      for (int tap = 0; tap < 9; ++tap) {
        const int iy = oy + tap / 3 - 1, ix = ox + tap - (tap / 3) * 3 - 1;
        int src = 112;                                           // dummy zero row
        if (iy >= 0 && iy < 15 && ix >= 0 && ix < 15) {
          const int sl = s.slotmap[iy * 15 + ix];
          if (sl >= 0) src = sl;
        }
        const uint4* abase = (const uint4*)&s.feat2[src * 116 + q * 4];
        const uint4* bbase = (const uint4*)&wst[tap * 1792 + m * 112 + q * 4];
        #pragma unroll
        for (int sp = 0; sp < 7; ++sp) {                         // 7 k-steps of 32
          U4H8 av, bv;
          av.u = abase[sp * 4];                                  // lds: A[m][32sp + q*8 + j]
          bv.u = bbase[sp * 4];                                  // L2:  B[32sp + q*8 + j][n]
          acc = __builtin_amdgcn_mfma_f32_16x16x32_f16(av.h, bv.h, acc, 0, 0, 0);
        }
      }
      #pragma unroll
      for (int r = 0; r < 4; ++r) {                              // D[row=q*4+r][col=m]
        const int orow = g * 16 + q * 4 + r;
        const int po = s.pts[orow];
        s.h1[po * 16 + m] = (_Float16)(acc[r] + bias);
      }
    }
  }
  __syncthreads();

  // ---- phase 4: pool1 3x3 s2 max-or -> h1p (7,7,16), m1 ----
  for (int i = t; i < 784; i += 256) {
    const int pp = i >> 4, c = i & 15;
    const int py = pp / 7, px = pp - py * 7;
    float mv = -1e30f;
    int msk = 0;
    #pragma unroll
    for (int ky = 0; ky < 3; ++ky)
      #pragma unroll
      for (int kx = 0; kx < 3; ++kx) {
        const int pos = (2 * py + ky) * 15 + (2 * px + kx);
        msk |= (s.slotmap[pos] >= 0) ? 1 : 0;
        mv = fmaxf(mv, (float)s.h1[pos * 16 + c]);
      }
    s.h1p[pp * 16 + c] = (_Float16)(msk ? mv : 0.f);
    if (c == 0) s.m1[pp] = (unsigned char)msk;
  }
  __syncthreads();

  // ---- phase 5: conv2 MFMA (waves 0,1: n-tiles) + m2 (wave 2) ----
  if (wv < 2) {
    const int n = lane & 15;
    const int q2 = lane >> 4;
    const int mrow = (n < 9) ? n : 8;                            // clamped A row
    const int aoy = mrow / 3, aox = mrow - aoy * 3;
    const int cch = wv * 16 + n;                                 // B col channel
    f32x4 acc = {0.f, 0.f, 0.f, 0.f};
    #pragma unroll
    for (int sp = 0; sp < 13; ++sp) {                            // K = 416 (tap 25 zero-wt)
      const int tap = 2 * sp + (q2 >> 1);
      const int ky = tap / 5, kx = tap - ky * 5;
      const int patch = (aoy + ky) * 7 + (aox + kx);             // <= 51, padded rows zero
      U4H8 av, bv;
      av.u = *(const uint4*)&s.h1p[patch * 16 + (q2 & 1) * 8];
      bv.u = *(const uint4*)&wst[W2T_OFF + cch * 208 + sp * 16 + q2 * 4];
      acc = __builtin_amdgcn_mfma_f32_16x16x32_f16(av.h, bv.h, acc, 0, 0, 0);
    }
    #pragma unroll
    for (int r = 0; r < 4; ++r) {
      const int row = q2 * 4 + r;
      if (row < 9) s.h2[row * 32 + cch] = acc[r];
    }
  } else if (wv == 2 && lane < 9) {
    const int oy = lane / 3, ox = lane - oy * 3;
    int any = 0;
    for (int ky = 0; ky < 5; ++ky)
      for (int kx = 0; kx < 5; ++kx)
        any |= s.m1[(oy + ky) * 7 + (ox + kx)];
    s.m2[lane] = (unsigned char)any;
  }
  __syncthreads();

  // ---- phase 6: pool2 (masked max over all 9) + head ----
  if (t < 32) {
    float best = -1e30f;
    int any = 0;
    #pragma unroll
    for (int pos = 0; pos < 9; ++pos) {
      if (s.m2[pos]) { any = 1; best = fmaxf(best, s.h2[pos * 32 + t]); }
    }
    s.vp[t] = any ? best : 0.f;
  }
  __syncthreads();

  if (t == 0) {
    float l0 = linb[0], l1 = linb[1];
    #pragma unroll
    for (int c = 0; c < 32; ++c) {
      const float v = s.vp[c];
      l0 = fmaf(v, linW[2 * c], l0);
      l1 = fmaf(v, linW[2 * c + 1], l1);
    }
    const float mx = fmaxf(l0, l1);
    const float e0 = expf(l0 - mx), e1 = expf(l1 - mx);
    const float inv = 1.0f / (e0 + e1);
    out[2 * b] = e0 * inv;
    out[2 * b + 1] = e1 * inv;
  }
}

extern "C" void kernel_launch(void* const* d_in, const int* in_sizes, int n_in,
                              void* d_out, int out_size, void* d_ws, size_t ws_size,
                              hipStream_t stream) {
  const int*   coords = (const int*)d_in[0];
  const float* feats  = (const float*)d_in[1];
  const float* W1     = (const float*)d_in[2];
  const float* b1     = (const float*)d_in[3];
  const float* W2     = (const float*)d_in[4];
  const float* linW   = (const float*)d_in[5];
  const float* linb   = (const float*)d_in[6];
  (void)n_in; (void)out_size; (void)ws_size;

  uint32_t* wst = (uint32_t*)d_ws;     // needs >= 92,160 B
  const int prep_items = W1T_WORDS + W2T_WORDS;
  prep_weights<<<dim3((prep_items + 255) / 256), dim3(256), 0, stream>>>(W1, W2, wst);

  const int B = in_sizes[0] / (112 * 3);
  spnet_main<<<dim3(B), dim3(256), 0, stream>>>(coords, feats, b1, linW, linb, wst, (float*)d_out);
}

// Round 3
// 540.802 us; speedup vs baseline: 1.6944x; 1.2646x over previous
//
#include <hip/hip_runtime.h>
#include <stdint.h>
#include <stddef.h>

// SparseNet on MI355X — R3: latency-focused restructure.
// * 3 blocks/CU (LDS 49.3 KB): feat rows = 100 words exactly; K-tail handled by
//   overlapping last k-step (base 168) with B-weights zeroed on the overlap.
// * Staging: fixed-trip unrolled load batches (MLP ~21 loads/lane in flight).
// * conv1: tap-outer loop, coalesced 1KB/wave B loads reused across 2 m-groups,
//   2 independent MFMA chains per wave.

typedef _Float16 f16x8 __attribute__((ext_vector_type(8)));
typedef float f32x4 __attribute__((ext_vector_type(4)));
union U4H8 { uint4 u; f16x8 h; };

#define W1V_WORDS (9 * 7 * 64 * 4)   // 16128 u32: [tap][sp][lane][w]
#define W2V_OFF   W1V_WORDS
#define W2V_WORDS (2 * 13 * 64 * 4)  // 6656 u32: [ntile][sp][lane][w]

extern "C" __global__ void prep_weights(const float* __restrict__ W1,
                                        const float* __restrict__ W2,
                                        uint32_t* __restrict__ ws) {
  const int j = blockIdx.x * 256 + threadIdx.x;
  constexpr int KB1[7] = {0, 32, 64, 96, 128, 160, 168};
  if (j < W1V_WORDS) {
    const int tap = j / 1792, r = j - tap * 1792;
    const int sp = r >> 8, r2 = r & 255;
    const int lane = r2 >> 2, w = r2 & 3;
    const int qq = lane >> 4, n = lane & 15;
    const int k0 = KB1[sp] + 8 * qq + 2 * w;
    // last k-step overlaps k 168..191 with step 5: zero B there (A data is real)
    const float f0 = (sp == 6 && k0     < 192) ? 0.f : W1[(tap * 200 + k0    ) * 16 + n];
    const float f1 = (sp == 6 && k0 + 1 < 192) ? 0.f : W1[(tap * 200 + k0 + 1) * 16 + n];
    union { uint32_t u; _Float16 h[2]; } p;
    p.h[0] = (_Float16)f0; p.h[1] = (_Float16)f1;
    ws[j] = p.u;
  } else if (j < W1V_WORDS + W2V_WORDS) {
    const int j2 = j - W1V_WORDS;
    const int nt = j2 / 3328, r = j2 - nt * 3328;
    const int sp = r >> 8, r2 = r & 255;
    const int lane = r2 >> 2, w = r2 & 3;
    const int qq = lane >> 4, n = lane & 15;
    const int col = nt * 16 + n;
    const int k0 = (sp < 12 ? 32 * sp : 368) + 8 * qq + 2 * w;
    // K=400: 13th step overlaps k 368..383 (tap 23): zero B on the overlap
    const float f0 = (sp == 12 && k0     < 384) ? 0.f : W2[(k0    ) * 32 + col];
    const float f1 = (sp == 12 && k0 + 1 < 384) ? 0.f : W2[(k0 + 1) * 32 + col];
    union { uint32_t u; _Float16 h[2]; } p;
    p.h[0] = (_Float16)f0; p.h[1] = (_Float16)f1;
    ws[W2V_OFF + j2] = p.u;
  }
}

struct __align__(16) SM {
  union {
    uint32_t feat2[113 * 100];     // [slot][50 x f16-pair words]; row 112 = zeros. 45200 B
    struct {                        // reused after conv1 completes:
      _Float16 h1p[49 * 16];        // pool1 out (7,7,16)
      float    h2[9 * 32];          // conv2 out (3,3,32)
      float    vp[32];              // pool2 out
    } p;
  } u;
  _Float16 h1s[112 * 16];           // conv1 out, slot-indexed. 3584 B
  short    slotmap[225];            // pos -> slot | -1. 450 B
  unsigned char m1[49];
  unsigned char m2[9];
};                                  // ~49.3 KB -> 3 blocks/CU

extern "C" __global__ void __launch_bounds__(256, 3)
spnet_main(const int* __restrict__ coords, const float* __restrict__ feats,
           const float* __restrict__ b1, const float* __restrict__ linW,
           const float* __restrict__ linb, const uint32_t* __restrict__ wst,
           float* __restrict__ out)
{
  __shared__ SM s;
  const int t = threadIdx.x, b = blockIdx.x;
  const int lane = t & 63, wv = t >> 6;
  const int m = lane & 15, q = lane >> 4;

  // ---- early global loads (issue before anything dependent) ----
  const int cbase = b * 112 * 3;
  int my_pos = 0;
  if (t < 112) {
    const int y = coords[cbase + t * 3], x = coords[cbase + t * 3 + 1];
    my_pos = y * 15 + x;
  }
  const int o0 = wv * 16 + m;               // m-group g0 = wv (0..3)
  const bool hg1 = (wv + 4) < 7;            // m-group g1 = wv+4 (4..6)
  const int o1 = hg1 ? (wv + 4) * 16 + m : o0;
  const int oy0 = coords[cbase + o0 * 3], ox0 = coords[cbase + o0 * 3 + 1];
  const int oy1 = coords[cbase + o1 * 3], ox1 = coords[cbase + o1 * 3 + 1];
  const float bias = b1[m];

  const float4* fsrc = (const float4*)(feats + (size_t)b * 22400);
  float4 va[11];
  #pragma unroll
  for (int k = 0; k < 11; ++k) va[k] = fsrc[t + k * 256];   // batch-1 loads in flight

  // ---- init (overlaps load latency) ----
  if (t < 225) s.slotmap[t] = -1;
  if (t < 100) s.u.feat2[112 * 100 + t] = 0;                // dummy zero row
  __syncthreads();

  if (t < 112) s.slotmap[my_pos] = (short)t;

  // ---- staging: batch-2 loads first, then all converts ----
  float4 vb[10];
  #pragma unroll
  for (int k = 0; k < 10; ++k) vb[k] = fsrc[t + (11 + k) * 256];
  const bool tl = t < 224;                                   // 5600 = 256*21 + 224
  float4 vt;
  if (tl) vt = fsrc[5376 + t];

  auto cvt_store = [&](int i, float4 v) {
    const int r = i / 50, c = i - r * 50;
    union { uint2 u2; _Float16 h[4]; } p;
    p.h[0] = (_Float16)v.x; p.h[1] = (_Float16)v.y;
    p.h[2] = (_Float16)v.z; p.h[3] = (_Float16)v.w;
    *(uint2*)&s.u.feat2[r * 100 + 2 * c] = p.u2;
  };
  #pragma unroll
  for (int k = 0; k < 11; ++k) cvt_store(t + k * 256, va[k]);
  #pragma unroll
  for (int k = 0; k < 10; ++k) cvt_store(t + (11 + k) * 256, vb[k]);
  if (tl) cvt_store(5376 + t, vt);
  __syncthreads();

  // ---- conv1: M=112 (7 groups of 16), N=16, K=200 via 7 k-steps ----
  auto look = [&](int iy, int ix) -> int {
    if (iy < 0 || iy > 14 || ix < 0 || ix > 14) return 112;
    const int sl = s.slotmap[iy * 15 + ix];
    return sl >= 0 ? sl : 112;
  };
  int src0[9], src1[9];
  #pragma unroll
  for (int tap = 0; tap < 9; ++tap) {
    const int ky = tap / 3 - 1, kx = tap % 3 - 1;
    src0[tap] = look(oy0 + ky, ox0 + kx);
    src1[tap] = hg1 ? look(oy1 + ky, ox1 + kx) : 112;
  }

  constexpr int WOFF[7] = {0, 16, 32, 48, 64, 80, 84};      // = KB1/2 (words)
  const uint4* w1v4 = (const uint4*)wst;
  f32x4 acc0 = {0.f, 0.f, 0.f, 0.f}, acc1 = {0.f, 0.f, 0.f, 0.f};
  #pragma unroll
  for (int tap = 0; tap < 9; ++tap) {
    f16x8 bv[7];
    #pragma unroll
    for (int sp = 0; sp < 7; ++sp) {
      U4H8 tmp; tmp.u = w1v4[(tap * 7 + sp) * 64 + lane];   // 1KB/wave contiguous
      bv[sp] = tmp.h;
    }
    const uint32_t* a0 = &s.u.feat2[src0[tap] * 100 + 4 * q];
    const uint32_t* a1 = &s.u.feat2[src1[tap] * 100 + 4 * q];
    #pragma unroll
    for (int sp = 0; sp < 7; ++sp) {
      U4H8 av; av.u = *(const uint4*)(a0 + WOFF[sp]);
      acc0 = __builtin_amdgcn_mfma_f32_16x16x32_f16(av.h, bv[sp], acc0, 0, 0, 0);
      U4H8 aw; aw.u = *(const uint4*)(a1 + WOFF[sp]);
      acc1 = __builtin_amdgcn_mfma_f32_16x16x32_f16(aw.h, bv[sp], acc1, 0, 0, 0);
    }
  }
  #pragma unroll
  for (int r = 0; r < 4; ++r)
    s.h1s[(wv * 16 + q * 4 + r) * 16 + m] = (_Float16)(acc0[r] + bias);
  if (hg1) {
    #pragma unroll
    for (int r = 0; r < 4; ++r)
      s.h1s[((wv + 4) * 16 + q * 4 + r) * 16 + m] = (_Float16)(acc1[r] + bias);
  }
  __syncthreads();

  // ---- pool1: 3x3 s2 masked max -> h1p (7,7,16) + m1 (feat2 region now dead) ----
  for (int i = t; i < 784; i += 256) {
    const int pp = i >> 4, c = i & 15;
    const int py = pp / 7, px = pp - py * 7;
    float mv = -1e30f;
    int msk = 0;
    #pragma unroll
    for (int ky = 0; ky < 3; ++ky)
      #pragma unroll
      for (int kx = 0; kx < 3; ++kx) {
        const int sl = s.slotmap[(2 * py + ky) * 15 + 2 * px + kx];
        if (sl >= 0) { msk = 1; mv = fmaxf(mv, (float)s.h1s[sl * 16 + c]); }
      }
    s.u.p.h1p[pp * 16 + c] = (_Float16)(msk ? mv : 0.f);
    if (c == 0) s.m1[pp] = (unsigned char)msk;
  }
  __syncthreads();

  // ---- conv2 (waves 0,1) MFMA M=9(pad16),N=16,K=400 in 13 steps; m2 (wave 2) ----
  if (wv < 2) {
    const int mr = (m < 9) ? m : 8;              // clamped A row (pool position)
    const int aoy = mr / 3, aox = mr - aoy * 3;
    const uint4* w2v4 = (const uint4*)(wst + W2V_OFF);
    f32x4 acc = {0.f, 0.f, 0.f, 0.f};
    #pragma unroll
    for (int sp = 0; sp < 13; ++sp) {
      const int tap = (sp < 12 ? 2 * sp : 23) + (q >> 1);
      const int ty = tap / 5, tx = tap - ty * 5;
      const int patch = (aoy + ty) * 7 + aox + tx;
      U4H8 av; av.u = *(const uint4*)&s.u.p.h1p[patch * 16 + (q & 1) * 8];
      U4H8 bv; bv.u = w2v4[(wv * 13 + sp) * 64 + lane];
      acc = __builtin_amdgcn_mfma_f32_16x16x32_f16(av.h, bv.h, acc, 0, 0, 0);
    }
    #pragma unroll
    for (int r = 0; r < 4; ++r) {
      const int row = q * 4 + r;
      if (row < 9) s.u.p.h2[row * 32 + wv * 16 + m] = acc[r];
    }
  } else if (wv == 2 && lane < 9) {
    const int oy = lane / 3, ox = lane - oy * 3;
    int any = 0;
    for (int ky = 0; ky < 5; ++ky)
      for (int kx = 0; kx < 5; ++kx)
        any |= s.m1[(oy + ky) * 7 + (ox + kx)];
    s.m2[lane] = (unsigned char)any;
  }
  __syncthreads();

  // ---- pool2: masked max over all 9 positions ----
  if (t < 32) {
    float best = -1e30f;
    int any = 0;
    #pragma unroll
    for (int pos = 0; pos < 9; ++pos)
      if (s.m2[pos]) { any = 1; best = fmaxf(best, s.u.p.h2[pos * 32 + t]); }
    s.u.p.vp[t] = any ? best : 0.f;
  }
  __syncthreads();

  // ---- head: 32 -> 2 linear + softmax ----
  if (t == 0) {
    float l0 = linb[0], l1 = linb[1];
    #pragma unroll
    for (int c = 0; c < 32; ++c) {
      const float v = s.u.p.vp[c];
      l0 = fmaf(v, linW[2 * c], l0);
      l1 = fmaf(v, linW[2 * c + 1], l1);
    }
    const float mx = fmaxf(l0, l1);
    const float e0 = expf(l0 - mx), e1 = expf(l1 - mx);
    const float inv = 1.0f / (e0 + e1);
    out[2 * b] = e0 * inv;
    out[2 * b + 1] = e1 * inv;
  }
}

extern "C" void kernel_launch(void* const* d_in, const int* in_sizes, int n_in,
                              void* d_out, int out_size, void* d_ws, size_t ws_size,
                              hipStream_t stream) {
  const int*   coords = (const int*)d_in[0];
  const float* feats  = (const float*)d_in[1];
  const float* W1     = (const float*)d_in[2];
  const float* b1     = (const float*)d_in[3];
  const float* W2     = (const float*)d_in[4];
  const float* linW   = (const float*)d_in[5];
  const float* linb   = (const float*)d_in[6];
  (void)n_in; (void)out_size; (void)ws_size;

  uint32_t* wst = (uint32_t*)d_ws;   // uses 91,136 B
  const int prep_items = W1V_WORDS + W2V_WORDS;   // 22784
  prep_weights<<<dim3((prep_items + 255) / 256), dim3(256), 0, stream>>>(W1, W2, wst);

  const int B = in_sizes[0] / (112 * 3);
  spnet_main<<<dim3(B), dim3(256), 0, stream>>>(coords, feats, b1, linW, linb, wst, (float*)d_out);
}

// Round 4
// 528.391 us; speedup vs baseline: 1.7342x; 1.0235x over previous
//
#include <hip/hip_runtime.h>
#include <stdint.h>
#include <stddef.h>

// SparseNet MI355X — R4: K-chunked double-buffered feature staging (6 chunks),
// 24.5 KB LDS + low VGPR -> 6 blocks/CU; pipelined global->LDS vs MFMA;
// srcOff u16 table replaces per-lane src registers.

typedef _Float16 f16x8 __attribute__((ext_vector_type(8)));
typedef float f32x4 __attribute__((ext_vector_type(4)));
union U4H8 { uint4 u; f16x8 h; };

#define W1V_WORDS (9 * 7 * 64 * 4)   // [tap][cs][lane][w], cs k-bases {0,32,64,96,128,160,168}
#define W2V_OFF   W1V_WORDS
#define W2V_WORDS (2 * 13 * 64 * 4)  // [ntile][sp][lane][w]

extern "C" __global__ void prep_weights(const float* __restrict__ W1,
                                        const float* __restrict__ W2,
                                        uint32_t* __restrict__ ws) {
  const int j = blockIdx.x * 256 + threadIdx.x;
  constexpr int KB1[7] = {0, 32, 64, 96, 128, 160, 168};
  if (j < W1V_WORDS) {
    const int tap = j / 1792, r = j - tap * 1792;
    const int sp = r >> 8, r2 = r & 255;
    const int lane = r2 >> 2, w = r2 & 3;
    const int qq = lane >> 4, n = lane & 15;
    const int k0 = KB1[sp] + 8 * qq + 2 * w;
    // cs=6 overlaps k 168..191 with cs=5: zero B there (A data is real)
    const float f0 = (sp == 6 && k0     < 192) ? 0.f : W1[(tap * 200 + k0    ) * 16 + n];
    const float f1 = (sp == 6 && k0 + 1 < 192) ? 0.f : W1[(tap * 200 + k0 + 1) * 16 + n];
    union { uint32_t u; _Float16 h[2]; } p;
    p.h[0] = (_Float16)f0; p.h[1] = (_Float16)f1;
    ws[j] = p.u;
  } else if (j < W1V_WORDS + W2V_WORDS) {
    const int j2 = j - W1V_WORDS;
    const int nt = j2 / 3328, r = j2 - nt * 3328;
    const int sp = r >> 8, r2 = r & 255;
    const int lane = r2 >> 2, w = r2 & 3;
    const int qq = lane >> 4, n = lane & 15;
    const int col = nt * 16 + n;
    const int k0 = (sp < 12 ? 32 * sp : 368) + 8 * qq + 2 * w;
    // K=400: 13th step overlaps k 368..383: zero B on the overlap
    const float f0 = (sp == 12 && k0     < 384) ? 0.f : W2[(k0    ) * 32 + col];
    const float f1 = (sp == 12 && k0 + 1 < 384) ? 0.f : W2[(k0 + 1) * 32 + col];
    union { uint32_t u; _Float16 h[2]; } p;
    p.h[0] = (_Float16)f0; p.h[1] = (_Float16)f1;
    ws[W2V_OFF + j2] = p.u;
  }
}

struct __align__(16) SM {
  union {
    uint32_t buf[2][113 * 20];        // chunk double-buffer; row 112 = zeros. 18080 B
    struct {                          // alive only after conv1:
      _Float16 h1p[49 * 16];          // pool1 out (7,7,16)
      float    h2[9 * 32];            // conv2 out
      float    vp[32];                // pool2 out
    } p;
  } u;
  _Float16 h1s[112 * 16];             // conv1 out, slot-indexed. 3584 B
  unsigned short srcOff[9 * 128];     // [tap][o] A-row byte offset (src*80); o>=112 -> dummy. 2304 B
  short slotmap[225];                 // 450 B
  unsigned char m1[49];
  unsigned char m2[9];
};                                    // ~24.5 KB -> 6 blocks/CU

__device__ __forceinline__ f32x4 MF(f16x8 a, f16x8 b, f32x4 c) {
  return __builtin_amdgcn_mfma_f32_16x16x32_f16(a, b, c, 0, 0, 0);
}

extern "C" __global__ void __launch_bounds__(256, 6)
spnet_main(const int* __restrict__ coords, const float* __restrict__ feats,
           const float* __restrict__ b1, const float* __restrict__ linW,
           const float* __restrict__ linb, const uint32_t* __restrict__ wst,
           float* __restrict__ out)
{
  __shared__ SM s;
  const int t = threadIdx.x, b = blockIdx.x;
  const int lane = t & 63, wv = t >> 6;
  const int m = lane & 15, q = lane >> 4;

  // ---- early independent global loads ----
  int my_pos = 0;
  if (t < 112) {
    const int cb = b * 336 + 3 * t;
    my_pos = coords[cb] * 15 + coords[cb + 1];
  }
  const float bias = b1[m];
  const float4* fsrc = (const float4*)(feats + (size_t)b * 22400);

  // chunk loaders/storers. chunks 0..4: 32 ch (8 f4/row); chunk 5: 40 ch (10 f4/row).
  auto ldC = [&](int c, float4* r) {            // c in 0..4
    #pragma unroll
    for (int k = 0; k < 3; ++k) { const int e = t + 256 * k; r[k] = fsrc[(e >> 3) * 50 + 8 * c + (e & 7)]; }
    if (t < 128) { const int e = t + 768; r[3] = fsrc[(e >> 3) * 50 + 8 * c + (e & 7)]; }
  };
  auto stC = [&](int bi, const float4* r) {
    char* base = (char*)&s.u.buf[bi][0];
    auto put = [&](int e, float4 v) {
      union { uint2 u2; _Float16 h[4]; } p;
      p.h[0] = (_Float16)v.x; p.h[1] = (_Float16)v.y;
      p.h[2] = (_Float16)v.z; p.h[3] = (_Float16)v.w;
      *(uint2*)(base + (e >> 3) * 80 + 8 * (e & 7)) = p.u2;
    };
    #pragma unroll
    for (int k = 0; k < 3; ++k) put(t + 256 * k, r[k]);
    if (t < 128) put(t + 768, r[3]);
  };
  auto ldC5 = [&](float4* r) {
    #pragma unroll
    for (int k = 0; k < 4; ++k) { const int e = t + 256 * k; const int row = e / 10; r[k] = fsrc[row * 50 + 40 + (e - 10 * row)]; }
    if (t < 96) { const int e = t + 1024; const int row = e / 10; r[4] = fsrc[row * 50 + 40 + (e - 10 * row)]; }
  };
  auto stC5 = [&](int bi, const float4* r) {
    char* base = (char*)&s.u.buf[bi][0];
    auto put = [&](int e, float4 v) {
      const int row = e / 10, col = e - 10 * row;
      union { uint2 u2; _Float16 h[4]; } p;
      p.h[0] = (_Float16)v.x; p.h[1] = (_Float16)v.y;
      p.h[2] = (_Float16)v.z; p.h[3] = (_Float16)v.w;
      *(uint2*)(base + row * 80 + 8 * col) = p.u2;
    };
    #pragma unroll
    for (int k = 0; k < 4; ++k) put(t + 256 * k, r[k]);
    if (t < 96) put(t + 1024, r[4]);
  };

  // ---- phase 1: chunk0 loads in flight; init slotmap + dummy rows ----
  float4 cur[5];
  ldC(0, cur);
  if (t < 225) s.slotmap[t] = -1;
  if (t < 40) s.u.buf[t / 20][112 * 20 + (t % 20)] = 0;   // zero dummy row, both buffers
  __syncthreads();
  if (t < 112) s.slotmap[my_pos] = (short)t;
  __syncthreads();

  // ---- phase 2: srcOff table + store chunk0 ----
  if (t < 128) {
    const int oy = my_pos / 15, ox = my_pos - (my_pos / 15) * 15;
    #pragma unroll
    for (int tap = 0; tap < 9; ++tap) {
      int srcv = 112;
      if (t < 112) {
        const int iy = oy + tap / 3 - 1, ix = ox + tap % 3 - 1;
        if (iy >= 0 && iy < 15 && ix >= 0 && ix < 15) {
          const int sl = s.slotmap[iy * 15 + ix];
          if (sl >= 0) srcv = sl;
        }
      }
      s.srcOff[tap * 128 + t] = (unsigned short)(srcv * 80);
    }
  }
  stC(0, cur);
  __syncthreads();

  // ---- conv1: 6-chunk pipelined MFMA. per wave: groups wv and wv+4 ----
  const uint4* w1v4 = (const uint4*)wst;
  const int o0 = wv * 16 + m, o1 = (wv + 4) * 16 + m;     // o1<=127: dummy rows for wv==3
  f32x4 acc0 = {0.f, 0.f, 0.f, 0.f}, acc1 = {0.f, 0.f, 0.f, 0.f};
  float4 nxt[5];

  for (int c = 0; c < 5; ++c) {
    if (c < 4) ldC(c + 1, nxt); else ldC5(nxt);           // prefetch next chunk
    const char* abase = (const char*)&s.u.buf[c & 1][0];
    #pragma unroll 3
    for (int tap = 0; tap < 9; ++tap) {
      U4H8 bv; bv.u = w1v4[(tap * 7 + c) * 64 + lane];    // 1KB/wave contiguous (L2/L1)
      const int f0 = s.srcOff[tap * 128 + o0];
      const int f1 = s.srcOff[tap * 128 + o1];
      U4H8 a0; a0.u = *(const uint4*)(abase + f0 + 16 * q);
      acc0 = MF(a0.h, bv.h, acc0);
      U4H8 a1; a1.u = *(const uint4*)(abase + f1 + 16 * q);
      acc1 = MF(a1.h, bv.h, acc1);
    }
    if (c < 4) stC(1 - (c & 1), nxt); else stC5(1 - (c & 1), nxt);
    __syncthreads();
  }
  { // chunk 5 (40 ch, k-steps cs=5 and cs=6 with zeroed overlap), buf[1]
    const char* abase = (const char*)&s.u.buf[1][0];
    #pragma unroll 3
    for (int tap = 0; tap < 9; ++tap) {
      U4H8 b0, b1v; b0.u = w1v4[(tap * 7 + 5) * 64 + lane]; b1v.u = w1v4[(tap * 7 + 6) * 64 + lane];
      const int f0 = s.srcOff[tap * 128 + o0];
      const int f1 = s.srcOff[tap * 128 + o1];
      U4H8 a;
      a.u = *(const uint4*)(abase + f0 + 16 * q);      acc0 = MF(a.h, b0.h, acc0);
      a.u = *(const uint4*)(abase + f0 + 16 * q + 16); acc0 = MF(a.h, b1v.h, acc0);
      a.u = *(const uint4*)(abase + f1 + 16 * q);      acc1 = MF(a.h, b0.h, acc1);
      a.u = *(const uint4*)(abase + f1 + 16 * q + 16); acc1 = MF(a.h, b1v.h, acc1);
    }
  }
  #pragma unroll
  for (int r = 0; r < 4; ++r)
    s.h1s[(wv * 16 + q * 4 + r) * 16 + m] = (_Float16)(acc0[r] + bias);
  if (wv < 3) {
    #pragma unroll
    for (int r = 0; r < 4; ++r)
      s.h1s[((wv + 4) * 16 + q * 4 + r) * 16 + m] = (_Float16)(acc1[r] + bias);
  }
  __syncthreads();

  // ---- pool1: 3x3 s2 masked max -> p.h1p (7,7,16) + m1 (buf region now dead) ----
  for (int i = t; i < 784; i += 256) {
    const int pp = i >> 4, c = i & 15;
    const int py = pp / 7, px = pp - py * 7;
    float mv = -1e30f;
    int msk = 0;
    #pragma unroll
    for (int ky = 0; ky < 3; ++ky)
      #pragma unroll
      for (int kx = 0; kx < 3; ++kx) {
        const int sl = s.slotmap[(2 * py + ky) * 15 + 2 * px + kx];
        if (sl >= 0) { msk = 1; mv = fmaxf(mv, (float)s.h1s[sl * 16 + c]); }
      }
    s.u.p.h1p[pp * 16 + c] = (_Float16)(msk ? mv : 0.f);
    if (c == 0) s.m1[pp] = (unsigned char)msk;
  }
  __syncthreads();

  // ---- conv2 (waves 0,1): M=9(pad16),N=16,K=400 in 13 steps; m2 on wave 2 ----
  if (wv < 2) {
    const int mr = (m < 9) ? m : 8;
    const int aoy = mr / 3, aox = mr - aoy * 3;
    const uint4* w2v4 = (const uint4*)(wst + W2V_OFF);
    f32x4 acc = {0.f, 0.f, 0.f, 0.f};
    #pragma unroll
    for (int sp = 0; sp < 13; ++sp) {
      const int tap = (sp < 12 ? 2 * sp : 23) + (q >> 1);
      const int ty = tap / 5, tx = tap - ty * 5;
      const int patch = (aoy + ty) * 7 + aox + tx;
      U4H8 av; av.u = *(const uint4*)&s.u.p.h1p[patch * 16 + (q & 1) * 8];
      U4H8 bv; bv.u = w2v4[(wv * 13 + sp) * 64 + lane];
      acc = MF(av.h, bv.h, acc);
    }
    #pragma unroll
    for (int r = 0; r < 4; ++r) {
      const int row = q * 4 + r;
      if (row < 9) s.u.p.h2[row * 32 + wv * 16 + m] = acc[r];
    }
  } else if (wv == 2 && lane < 9) {
    const int oy = lane / 3, ox = lane - oy * 3;
    int any = 0;
    for (int ky = 0; ky < 5; ++ky)
      for (int kx = 0; kx < 5; ++kx)
        any |= s.m1[(oy + ky) * 7 + (ox + kx)];
    s.m2[lane] = (unsigned char)any;
  }
  __syncthreads();

  // ---- pool2 + head ----
  if (t < 32) {
    float best = -1e30f;
    int any = 0;
    #pragma unroll
    for (int pos = 0; pos < 9; ++pos)
      if (s.m2[pos]) { any = 1; best = fmaxf(best, s.u.p.h2[pos * 32 + t]); }
    s.u.p.vp[t] = any ? best : 0.f;
  }
  __syncthreads();

  if (t == 0) {
    float l0 = linb[0], l1 = linb[1];
    #pragma unroll
    for (int c = 0; c < 32; ++c) {
      const float v = s.u.p.vp[c];
      l0 = fmaf(v, linW[2 * c], l0);
      l1 = fmaf(v, linW[2 * c + 1], l1);
    }
    const float mx = fmaxf(l0, l1);
    const float e0 = expf(l0 - mx), e1 = expf(l1 - mx);
    const float inv = 1.0f / (e0 + e1);
    out[2 * b] = e0 * inv;
    out[2 * b + 1] = e1 * inv;
  }
}

extern "C" void kernel_launch(void* const* d_in, const int* in_sizes, int n_in,
                              void* d_out, int out_size, void* d_ws, size_t ws_size,
                              hipStream_t stream) {
  const int*   coords = (const int*)d_in[0];
  const float* feats  = (const float*)d_in[1];
  const float* W1     = (const float*)d_in[2];
  const float* b1     = (const float*)d_in[3];
  const float* W2     = (const float*)d_in[4];
  const float* linW   = (const float*)d_in[5];
  const float* linb   = (const float*)d_in[6];
  (void)n_in; (void)out_size; (void)ws_size;

  uint32_t* wst = (uint32_t*)d_ws;   // uses 91,136 B
  const int prep_items = W1V_WORDS + W2V_WORDS;
  prep_weights<<<dim3((prep_items + 255) / 256), dim3(256), 0, stream>>>(W1, W2, wst);

  const int B = in_sizes[0] / (112 * 3);
  spnet_main<<<dim3(B), dim3(256), 0, stream>>>(coords, feats, b1, linW, linb, wst, (float*)d_out);
}